// Round 4
// baseline (1124.982 us; speedup 1.0000x reference)
//
#include <hip/hip_runtime.h>

// SparseAffinity_Propagate: CSPN-style 8-neighbor propagation, 24 iterations.
// B=8, H=W=768. Offsets (dy,dx): (-5,0)(-1,0)(0,5)(0,1)(5,0)(1,0)(0,-5)(0,-1)
//
// Fusion (R0): result = sum_c (A*w_c) * prev[p+off_c] + Bias
// R1: weights fp16 AoS (16 B/px), bias fp32 -> 28 B/px per step.
// R2: 4 px/thread, aligned 16B vectors. (neutral -> not request-bound)
// R3: XCD swizzle: 1D grid, b = blk&7, y = blk>>3 -> batch k lives on XCD k
//     (prev/bias/result XCD-local, L2-resident across steps); weights loaded
//     nontemporal so the 9.4 MB/XCD/step stream doesn't evict them.

#define HH 768
#define WW 768
#define BATCH 8
#define PLANE (HH * WW)           // 589824
#define TOTAL (BATCH * PLANE)     // 4718592
#define NITER 24

#define DYS {-5, -1, 0, 0, 5, 1, 0, 0}
#define DXS {0, 0, 5, 1, 0, 0, -5, -1}

typedef _Float16 half8 __attribute__((ext_vector_type(8)));
typedef float f4 __attribute__((ext_vector_type(4)));

__device__ __forceinline__ f4 ldf4(const float* p) { return *(const f4*)p; }

// ---------------------------------------------------------------------------
// Precompute pre-scaled weights (fp16 AoS, 16 B/px) + fp32 bias.
// Block = 192 threads = one row (4 px/thread). Grid (1, 768, 8).
// ---------------------------------------------------------------------------
__global__ __launch_bounds__(192) void precompute_kernel(
    const float* __restrict__ g,       // (B,8,H,W)
    const float* __restrict__ blur,    // (B,1,H,W)
    const float* __restrict__ sparse,  // (B,1,H,W)
    half8* __restrict__ wout,          // (B*H*W) x 8 fp16  (AoS)
    float* __restrict__ bias)          // (B*H*W)
{
    const int x0 = 4 * threadIdx.x;
    const int y  = blockIdx.y;
    const int b  = blockIdx.z;
    const float* gb = g + (size_t)b * 8 * PLANE;
    const int rowb = y * WW;
    const int pidx = b * PLANE + rowb + x0;

    f4 wv[8];
    if (x0 >= 8 && x0 <= 756) {
        const f4 zero = (f4)0.f;
        wv[0] = (y >= 5)      ? ldf4(gb + 0 * PLANE + (y - 5) * WW + x0) : zero;
        wv[1] = (y >= 1)      ? ldf4(gb + 1 * PLANE + (y - 1) * WW + x0) : zero;
        wv[4] = (y <= HH - 6) ? ldf4(gb + 4 * PLANE + (y + 5) * WW + x0) : zero;
        wv[5] = (y <= HH - 2) ? ldf4(gb + 5 * PLANE + (y + 1) * WW + x0) : zero;
        {   // c=2, dx=+5
            f4 a = ldf4(gb + 2 * PLANE + rowb + x0 + 4);
            f4 bq = ldf4(gb + 2 * PLANE + rowb + x0 + 8);
            wv[2] = f4{a[1], a[2], a[3], bq[0]};
        }
        {   // c=3, dx=+1
            f4 a = ldf4(gb + 3 * PLANE + rowb + x0);
            f4 bq = ldf4(gb + 3 * PLANE + rowb + x0 + 4);
            wv[3] = f4{a[1], a[2], a[3], bq[0]};
        }
        {   // c=6, dx=-5
            f4 a = ldf4(gb + 6 * PLANE + rowb + x0 - 8);
            f4 bq = ldf4(gb + 6 * PLANE + rowb + x0 - 4);
            wv[6] = f4{a[3], bq[0], bq[1], bq[2]};
        }
        {   // c=7, dx=-1
            f4 a = ldf4(gb + 7 * PLANE + rowb + x0 - 4);
            f4 bq = ldf4(gb + 7 * PLANE + rowb + x0);
            wv[7] = f4{a[3], bq[0], bq[1], bq[2]};
        }
    } else {
        const int dy[8] = DYS;
        const int dx[8] = DXS;
#pragma unroll
        for (int c = 0; c < 8; ++c) {
#pragma unroll
            for (int j = 0; j < 4; ++j) {
                int yy = y + dy[c];
                int xx = x0 + j + dx[c];
                float v = 0.f;
                if (yy >= 0 && yy < HH && xx >= 0 && xx < WW)
                    v = gb[c * PLANE + yy * WW + xx];
                wv[c][j] = v;
            }
        }
    }

    f4 raw = ldf4(blur + pidx);
    f4 sd  = ldf4(sparse + pidx);
    f4 bout;
#pragma unroll
    for (int j = 0; j < 4; ++j) {
        float abssum = 0.f;
#pragma unroll
        for (int c = 0; c < 8; ++c) abssum += fabsf(wv[c][j]);
        float inv = 1.f / fmaxf(abssum, 1e-6f);
        float gs = 0.f;
#pragma unroll
        for (int c = 0; c < 8; ++c) gs += wv[c][j] * inv;
        float s = sd[j];
        float m = (s > 0.f) ? 1.f : ((s < 0.f) ? -1.f : 0.f);
        float A = 1.f - m;
        bout[j] = (A * (1.f - gs) + m) * raw[j];
        float Ai = A * inv;
        half8 hv;
#pragma unroll
        for (int c = 0; c < 8; ++c) hv[c] = (_Float16)(Ai * wv[c][j]);
        wout[pidx + j] = hv;
    }
    *(f4*)(bias + pidx) = bout;
}

// ---------------------------------------------------------------------------
// One propagation step: out = sum_c w_c * prev[p+off_c] + bias
// 1D grid of 6144 blocks, 192 threads (one row, 4 px/thread).
// XCD swizzle: b = blk&7, y = blk>>3  (batch k -> XCD k under %8 round-robin)
// ---------------------------------------------------------------------------
__global__ __launch_bounds__(192) void step_kernel(
    const half8* __restrict__ w,     // (B*H*W) x 8 fp16
    const float* __restrict__ bias,  // (B*H*W)
    const float* __restrict__ prev,  // (B,H,W)
    float* __restrict__ next)        // (B,H,W)
{
    const int x0 = 4 * threadIdx.x;
    const int blk = blockIdx.x;
    const int b  = blk & 7;          // XCD-local batch
    const int y  = blk >> 3;
    const int rowb = y * WW;
    const int pidx = b * PLANE + rowb + x0;
    const float* pb = prev + b * PLANE;

    // Weights: pure stream, no intra-step reuse -> nontemporal (protect L2)
    half8 hv0 = __builtin_nontemporal_load(w + pidx + 0);
    half8 hv1 = __builtin_nontemporal_load(w + pidx + 1);
    half8 hv2 = __builtin_nontemporal_load(w + pidx + 2);
    half8 hv3 = __builtin_nontemporal_load(w + pidx + 3);
    f4 acc = ldf4(bias + pidx);

    if (x0 >= 8 && x0 <= 756) {
        const f4 zero = (f4)0.f;
        f4 um5 = (y >= 5)      ? ldf4(pb + (y - 5) * WW + x0) : zero;
        f4 um1 = (y >= 1)      ? ldf4(pb + (y - 1) * WW + x0) : zero;
        f4 dp5 = (y <= HH - 6) ? ldf4(pb + (y + 5) * WW + x0) : zero;
        f4 dp1 = (y <= HH - 2) ? ldf4(pb + (y + 1) * WW + x0) : zero;
        f4 m2 = ldf4(pb + rowb + x0 - 8);
        f4 m1 = ldf4(pb + rowb + x0 - 4);
        f4 c0 = ldf4(pb + rowb + x0);
        f4 p1 = ldf4(pb + rowb + x0 + 4);
        f4 p2 = ldf4(pb + rowb + x0 + 8);
        f4 tm5 = f4{m2[3], m1[0], m1[1], m1[2]};   // dx=-5
        f4 tm1 = f4{m1[3], c0[0], c0[1], c0[2]};   // dx=-1
        f4 tp1 = f4{c0[1], c0[2], c0[3], p1[0]};   // dx=+1
        f4 tp5 = f4{p1[1], p1[2], p1[3], p2[0]};   // dx=+5

        acc[0] = fmaf((float)hv0[0], um5[0], acc[0]);
        acc[1] = fmaf((float)hv1[0], um5[1], acc[1]);
        acc[2] = fmaf((float)hv2[0], um5[2], acc[2]);
        acc[3] = fmaf((float)hv3[0], um5[3], acc[3]);

        acc[0] = fmaf((float)hv0[1], um1[0], acc[0]);
        acc[1] = fmaf((float)hv1[1], um1[1], acc[1]);
        acc[2] = fmaf((float)hv2[1], um1[2], acc[2]);
        acc[3] = fmaf((float)hv3[1], um1[3], acc[3]);

        acc[0] = fmaf((float)hv0[2], tp5[0], acc[0]);
        acc[1] = fmaf((float)hv1[2], tp5[1], acc[1]);
        acc[2] = fmaf((float)hv2[2], tp5[2], acc[2]);
        acc[3] = fmaf((float)hv3[2], tp5[3], acc[3]);

        acc[0] = fmaf((float)hv0[3], tp1[0], acc[0]);
        acc[1] = fmaf((float)hv1[3], tp1[1], acc[1]);
        acc[2] = fmaf((float)hv2[3], tp1[2], acc[2]);
        acc[3] = fmaf((float)hv3[3], tp1[3], acc[3]);

        acc[0] = fmaf((float)hv0[4], dp5[0], acc[0]);
        acc[1] = fmaf((float)hv1[4], dp5[1], acc[1]);
        acc[2] = fmaf((float)hv2[4], dp5[2], acc[2]);
        acc[3] = fmaf((float)hv3[4], dp5[3], acc[3]);

        acc[0] = fmaf((float)hv0[5], dp1[0], acc[0]);
        acc[1] = fmaf((float)hv1[5], dp1[1], acc[1]);
        acc[2] = fmaf((float)hv2[5], dp1[2], acc[2]);
        acc[3] = fmaf((float)hv3[5], dp1[3], acc[3]);

        acc[0] = fmaf((float)hv0[6], tm5[0], acc[0]);
        acc[1] = fmaf((float)hv1[6], tm5[1], acc[1]);
        acc[2] = fmaf((float)hv2[6], tm5[2], acc[2]);
        acc[3] = fmaf((float)hv3[6], tm5[3], acc[3]);

        acc[0] = fmaf((float)hv0[7], tm1[0], acc[0]);
        acc[1] = fmaf((float)hv1[7], tm1[1], acc[1]);
        acc[2] = fmaf((float)hv2[7], tm1[2], acc[2]);
        acc[3] = fmaf((float)hv3[7], tm1[3], acc[3]);
    } else {
        const int dy[8] = DYS;
        const int dx[8] = DXS;
        half8 hvs[4] = {hv0, hv1, hv2, hv3};
#pragma unroll
        for (int j = 0; j < 4; ++j) {
#pragma unroll
            for (int c = 0; c < 8; ++c) {
                int yy = y + dy[c];
                int xx = x0 + j + dx[c];
                float n = 0.f;
                if (yy >= 0 && yy < HH && xx >= 0 && xx < WW)
                    n = pb[yy * WW + xx];
                acc[j] = fmaf((float)hvs[j][c], n, acc[j]);
            }
        }
    }
    *(f4*)(next + pidx) = acc;
}

// ---------------------------------------------------------------------------
// Fallback step (small ws): recompute weights/bias from inputs every step.
// ---------------------------------------------------------------------------
__global__ __launch_bounds__(256) void step_recompute_kernel(
    const float* __restrict__ g,
    const float* __restrict__ blur,
    const float* __restrict__ sparse,
    const float* __restrict__ prev,
    float* __restrict__ next)
{
    const int dy[8] = DYS;
    const int dx[8] = DXS;
    int x = blockIdx.x * blockDim.x + threadIdx.x;
    int y = blockIdx.y;
    int b = blockIdx.z;
    if (x >= WW) return;

    const float* gb = g + (size_t)b * 8 * PLANE;
    float w[8];
    float abssum = 0.f;
#pragma unroll
    for (int c = 0; c < 8; ++c) {
        int yy = y + dy[c];
        int xx = x + dx[c];
        float v = 0.f;
        if (yy >= 0 && yy < HH && xx >= 0 && xx < WW)
            v = gb[c * PLANE + yy * WW + xx];
        w[c] = v;
        abssum += fabsf(v);
    }
    float inv = 1.f / fmaxf(abssum, 1e-6f);
    float gs = 0.f;
#pragma unroll
    for (int c = 0; c < 8; ++c) {
        w[c] *= inv;
        gs += w[c];
    }
    int pidx = b * PLANE + y * WW + x;
    float sd = sparse[pidx];
    float m = (sd > 0.f) ? 1.f : ((sd < 0.f) ? -1.f : 0.f);
    float A = 1.f - m;
    float raw = blur[pidx];

    const float* pb = prev + b * PLANE;
    float acc = 0.f;
#pragma unroll
    for (int c = 0; c < 8; ++c) {
        int yy = y + dy[c];
        int xx = x + dx[c];
        float n = 0.f;
        if (yy >= 0 && yy < HH && xx >= 0 && xx < WW)
            n = pb[yy * WW + xx];
        acc = fmaf(A * w[c], n, acc);
    }
    next[pidx] = acc + (A * (1.f - gs) + m) * raw;
}

// ---------------------------------------------------------------------------
extern "C" void kernel_launch(void* const* d_in, const int* in_sizes, int n_in,
                              void* d_out, int out_size, void* d_ws, size_t ws_size,
                              hipStream_t stream) {
    const float* g      = (const float*)d_in[0];  // guidance (B,8,H,W)
    const float* blur   = (const float*)d_in[1];  // blur_depth (B,1,H,W)
    const float* sparse = (const float*)d_in[2];  // sparse_depth (B,1,H,W)
    float* out = (float*)d_out;

    dim3 block(192, 1, 1);           // one row, 4 px/thread
    dim3 gridPre(1, HH, BATCH);      // precompute: 2D
    dim3 gridStep(BATCH * HH, 1, 1); // step: 1D swizzled (6144 blocks)

    // fast path: fp16 AoS weights (16 B/px) + fp32 bias + ping buffer
    const size_t need_fast = (size_t)TOTAL * 16 + (size_t)TOTAL * 4 * 2;

    if (ws_size >= need_fast) {
        half8* w    = (half8*)d_ws;                       // TOTAL x 16 B
        float* bias = (float*)((char*)d_ws + (size_t)TOTAL * 16);
        float* r0   = bias + TOTAL;

        precompute_kernel<<<gridPre, block, 0, stream>>>(g, blur, sparse, w, bias);

        const float* prev = blur;
        for (int it = 0; it < NITER; ++it) {
            float* nxt = (it % 2 == 0) ? r0 : out;  // it=23 -> out
            step_kernel<<<gridStep, block, 0, stream>>>(w, bias, prev, nxt);
            prev = nxt;
        }
    } else {
        // Fallback: only one ping buffer in ws; recompute weights each step.
        dim3 block2(256, 1, 1);
        dim3 grid2(WW / 256, HH, BATCH);
        float* r0 = (float*)d_ws;
        const float* prev = blur;
        for (int it = 0; it < NITER; ++it) {
            float* nxt = (it % 2 == 0) ? r0 : out;
            step_recompute_kernel<<<grid2, block2, 0, stream>>>(g, blur, sparse,
                                                                prev, nxt);
            prev = nxt;
        }
    }
}

// Round 5
// 955.810 us; speedup vs baseline: 1.1770x; 1.1770x over previous
//
#include <hip/hip_runtime.h>

// SparseAffinity_Propagate: CSPN-style 8-neighbor propagation, 24 iterations.
// B=8, H=W=768. Offsets (dy,dx): (-5,0)(-1,0)(0,5)(0,1)(5,0)(1,0)(0,-5)(0,-1)
//
// Fusion (R0): result = sum_c (A*w_c) * prev[p+off_c] + Bias
// R1: weights fp16 AoS (16 B/px), bias fp32 -> 28 B/px per step.
// R2: 4 px/thread, aligned 16B vectors. (neutral -> not request-bound)
// R3: XCD swizzle + nontemporal weights -> REGRESSED (+7.2 us/step; NT loads
//     forced the 75.5 MB/step weight stream to HBM). R4: full revert of the
//     step path to the 953-us config; precompute split into 4 dispatches
//     (~24 us each) so step_kernel finally appears in rocprof top-5.

#define HH 768
#define WW 768
#define BATCH 8
#define PLANE (HH * WW)           // 589824
#define TOTAL (BATCH * PLANE)     // 4718592
#define NITER 24

#define DYS {-5, -1, 0, 0, 5, 1, 0, 0}
#define DXS {0, 0, 5, 1, 0, 0, -5, -1}

typedef _Float16 half8 __attribute__((ext_vector_type(8)));
typedef float f4 __attribute__((ext_vector_type(4)));

__device__ __forceinline__ f4 ldf4(const float* p) { return *(const f4*)p; }

// ---------------------------------------------------------------------------
// Precompute pre-scaled weights (fp16 AoS, 16 B/px) + fp32 bias.
// Block = 192 threads = one row (4 px/thread). Grid (1, 768, 2), 4 launches
// with b0 = 0,2,4,6 (split so step_kernel dominates rocprof top-5).
// ---------------------------------------------------------------------------
__global__ __launch_bounds__(192) void precompute_kernel(
    const float* __restrict__ g,       // (B,8,H,W)
    const float* __restrict__ blur,    // (B,1,H,W)
    const float* __restrict__ sparse,  // (B,1,H,W)
    half8* __restrict__ wout,          // (B*H*W) x 8 fp16  (AoS)
    float* __restrict__ bias,          // (B*H*W)
    int b0)
{
    const int x0 = 4 * threadIdx.x;
    const int y  = blockIdx.y;
    const int b  = blockIdx.z + b0;
    const float* gb = g + (size_t)b * 8 * PLANE;
    const int rowb = y * WW;
    const int pidx = b * PLANE + rowb + x0;

    f4 wv[8];
    if (x0 >= 8 && x0 <= 756) {
        const f4 zero = (f4)0.f;
        wv[0] = (y >= 5)      ? ldf4(gb + 0 * PLANE + (y - 5) * WW + x0) : zero;
        wv[1] = (y >= 1)      ? ldf4(gb + 1 * PLANE + (y - 1) * WW + x0) : zero;
        wv[4] = (y <= HH - 6) ? ldf4(gb + 4 * PLANE + (y + 5) * WW + x0) : zero;
        wv[5] = (y <= HH - 2) ? ldf4(gb + 5 * PLANE + (y + 1) * WW + x0) : zero;
        {   // c=2, dx=+5
            f4 a = ldf4(gb + 2 * PLANE + rowb + x0 + 4);
            f4 bq = ldf4(gb + 2 * PLANE + rowb + x0 + 8);
            wv[2] = f4{a[1], a[2], a[3], bq[0]};
        }
        {   // c=3, dx=+1
            f4 a = ldf4(gb + 3 * PLANE + rowb + x0);
            f4 bq = ldf4(gb + 3 * PLANE + rowb + x0 + 4);
            wv[3] = f4{a[1], a[2], a[3], bq[0]};
        }
        {   // c=6, dx=-5
            f4 a = ldf4(gb + 6 * PLANE + rowb + x0 - 8);
            f4 bq = ldf4(gb + 6 * PLANE + rowb + x0 - 4);
            wv[6] = f4{a[3], bq[0], bq[1], bq[2]};
        }
        {   // c=7, dx=-1
            f4 a = ldf4(gb + 7 * PLANE + rowb + x0 - 4);
            f4 bq = ldf4(gb + 7 * PLANE + rowb + x0);
            wv[7] = f4{a[3], bq[0], bq[1], bq[2]};
        }
    } else {
        const int dy[8] = DYS;
        const int dx[8] = DXS;
#pragma unroll
        for (int c = 0; c < 8; ++c) {
#pragma unroll
            for (int j = 0; j < 4; ++j) {
                int yy = y + dy[c];
                int xx = x0 + j + dx[c];
                float v = 0.f;
                if (yy >= 0 && yy < HH && xx >= 0 && xx < WW)
                    v = gb[c * PLANE + yy * WW + xx];
                wv[c][j] = v;
            }
        }
    }

    f4 raw = ldf4(blur + pidx);
    f4 sd  = ldf4(sparse + pidx);
    f4 bout;
#pragma unroll
    for (int j = 0; j < 4; ++j) {
        float abssum = 0.f;
#pragma unroll
        for (int c = 0; c < 8; ++c) abssum += fabsf(wv[c][j]);
        float inv = 1.f / fmaxf(abssum, 1e-6f);
        float gs = 0.f;
#pragma unroll
        for (int c = 0; c < 8; ++c) gs += wv[c][j] * inv;
        float s = sd[j];
        float m = (s > 0.f) ? 1.f : ((s < 0.f) ? -1.f : 0.f);
        float A = 1.f - m;
        bout[j] = (A * (1.f - gs) + m) * raw[j];
        float Ai = A * inv;
        half8 hv;
#pragma unroll
        for (int c = 0; c < 8; ++c) hv[c] = (_Float16)(Ai * wv[c][j]);
        wout[pidx + j] = hv;
    }
    *(f4*)(bias + pidx) = bout;
}

// ---------------------------------------------------------------------------
// One propagation step: out = sum_c w_c * prev[p+off_c] + bias
// Block = 192 threads = one row (4 px/thread). Grid (1, 768, 8).  [R3 config]
// ---------------------------------------------------------------------------
__global__ __launch_bounds__(192) void step_kernel(
    const half8* __restrict__ w,     // (B*H*W) x 8 fp16
    const float* __restrict__ bias,  // (B*H*W)
    const float* __restrict__ prev,  // (B,H,W)
    float* __restrict__ next)        // (B,H,W)
{
    const int x0 = 4 * threadIdx.x;
    const int y  = blockIdx.y;
    const int b  = blockIdx.z;
    const int rowb = y * WW;
    const int pidx = b * PLANE + rowb + x0;
    const float* pb = prev + b * PLANE;

    half8 hv0 = w[pidx + 0];
    half8 hv1 = w[pidx + 1];
    half8 hv2 = w[pidx + 2];
    half8 hv3 = w[pidx + 3];
    f4 acc = ldf4(bias + pidx);

    if (x0 >= 8 && x0 <= 756) {
        const f4 zero = (f4)0.f;
        f4 um5 = (y >= 5)      ? ldf4(pb + (y - 5) * WW + x0) : zero;
        f4 um1 = (y >= 1)      ? ldf4(pb + (y - 1) * WW + x0) : zero;
        f4 dp5 = (y <= HH - 6) ? ldf4(pb + (y + 5) * WW + x0) : zero;
        f4 dp1 = (y <= HH - 2) ? ldf4(pb + (y + 1) * WW + x0) : zero;
        f4 m2 = ldf4(pb + rowb + x0 - 8);
        f4 m1 = ldf4(pb + rowb + x0 - 4);
        f4 c0 = ldf4(pb + rowb + x0);
        f4 p1 = ldf4(pb + rowb + x0 + 4);
        f4 p2 = ldf4(pb + rowb + x0 + 8);
        f4 tm5 = f4{m2[3], m1[0], m1[1], m1[2]};   // dx=-5
        f4 tm1 = f4{m1[3], c0[0], c0[1], c0[2]};   // dx=-1
        f4 tp1 = f4{c0[1], c0[2], c0[3], p1[0]};   // dx=+1
        f4 tp5 = f4{p1[1], p1[2], p1[3], p2[0]};   // dx=+5

        acc[0] = fmaf((float)hv0[0], um5[0], acc[0]);
        acc[1] = fmaf((float)hv1[0], um5[1], acc[1]);
        acc[2] = fmaf((float)hv2[0], um5[2], acc[2]);
        acc[3] = fmaf((float)hv3[0], um5[3], acc[3]);

        acc[0] = fmaf((float)hv0[1], um1[0], acc[0]);
        acc[1] = fmaf((float)hv1[1], um1[1], acc[1]);
        acc[2] = fmaf((float)hv2[1], um1[2], acc[2]);
        acc[3] = fmaf((float)hv3[1], um1[3], acc[3]);

        acc[0] = fmaf((float)hv0[2], tp5[0], acc[0]);
        acc[1] = fmaf((float)hv1[2], tp5[1], acc[1]);
        acc[2] = fmaf((float)hv2[2], tp5[2], acc[2]);
        acc[3] = fmaf((float)hv3[2], tp5[3], acc[3]);

        acc[0] = fmaf((float)hv0[3], tp1[0], acc[0]);
        acc[1] = fmaf((float)hv1[3], tp1[1], acc[1]);
        acc[2] = fmaf((float)hv2[3], tp1[2], acc[2]);
        acc[3] = fmaf((float)hv3[3], tp1[3], acc[3]);

        acc[0] = fmaf((float)hv0[4], dp5[0], acc[0]);
        acc[1] = fmaf((float)hv1[4], dp5[1], acc[1]);
        acc[2] = fmaf((float)hv2[4], dp5[2], acc[2]);
        acc[3] = fmaf((float)hv3[4], dp5[3], acc[3]);

        acc[0] = fmaf((float)hv0[5], dp1[0], acc[0]);
        acc[1] = fmaf((float)hv1[5], dp1[1], acc[1]);
        acc[2] = fmaf((float)hv2[5], dp1[2], acc[2]);
        acc[3] = fmaf((float)hv3[5], dp1[3], acc[3]);

        acc[0] = fmaf((float)hv0[6], tm5[0], acc[0]);
        acc[1] = fmaf((float)hv1[6], tm5[1], acc[1]);
        acc[2] = fmaf((float)hv2[6], tm5[2], acc[2]);
        acc[3] = fmaf((float)hv3[6], tm5[3], acc[3]);

        acc[0] = fmaf((float)hv0[7], tm1[0], acc[0]);
        acc[1] = fmaf((float)hv1[7], tm1[1], acc[1]);
        acc[2] = fmaf((float)hv2[7], tm1[2], acc[2]);
        acc[3] = fmaf((float)hv3[7], tm1[3], acc[3]);
    } else {
        const int dy[8] = DYS;
        const int dx[8] = DXS;
        half8 hvs[4] = {hv0, hv1, hv2, hv3};
#pragma unroll
        for (int j = 0; j < 4; ++j) {
#pragma unroll
            for (int c = 0; c < 8; ++c) {
                int yy = y + dy[c];
                int xx = x0 + j + dx[c];
                float n = 0.f;
                if (yy >= 0 && yy < HH && xx >= 0 && xx < WW)
                    n = pb[yy * WW + xx];
                acc[j] = fmaf((float)hvs[j][c], n, acc[j]);
            }
        }
    }
    *(f4*)(next + pidx) = acc;
}

// ---------------------------------------------------------------------------
// Fallback step (small ws): recompute weights/bias from inputs every step.
// ---------------------------------------------------------------------------
__global__ __launch_bounds__(256) void step_recompute_kernel(
    const float* __restrict__ g,
    const float* __restrict__ blur,
    const float* __restrict__ sparse,
    const float* __restrict__ prev,
    float* __restrict__ next)
{
    const int dy[8] = DYS;
    const int dx[8] = DXS;
    int x = blockIdx.x * blockDim.x + threadIdx.x;
    int y = blockIdx.y;
    int b = blockIdx.z;
    if (x >= WW) return;

    const float* gb = g + (size_t)b * 8 * PLANE;
    float w[8];
    float abssum = 0.f;
#pragma unroll
    for (int c = 0; c < 8; ++c) {
        int yy = y + dy[c];
        int xx = x + dx[c];
        float v = 0.f;
        if (yy >= 0 && yy < HH && xx >= 0 && xx < WW)
            v = gb[c * PLANE + yy * WW + xx];
        w[c] = v;
        abssum += fabsf(v);
    }
    float inv = 1.f / fmaxf(abssum, 1e-6f);
    float gs = 0.f;
#pragma unroll
    for (int c = 0; c < 8; ++c) {
        w[c] *= inv;
        gs += w[c];
    }
    int pidx = b * PLANE + y * WW + x;
    float sd = sparse[pidx];
    float m = (sd > 0.f) ? 1.f : ((sd < 0.f) ? -1.f : 0.f);
    float A = 1.f - m;
    float raw = blur[pidx];

    const float* pb = prev + b * PLANE;
    float acc = 0.f;
#pragma unroll
    for (int c = 0; c < 8; ++c) {
        int yy = y + dy[c];
        int xx = x + dx[c];
        float n = 0.f;
        if (yy >= 0 && yy < HH && xx >= 0 && xx < WW)
            n = pb[yy * WW + xx];
        acc = fmaf(A * w[c], n, acc);
    }
    next[pidx] = acc + (A * (1.f - gs) + m) * raw;
}

// ---------------------------------------------------------------------------
extern "C" void kernel_launch(void* const* d_in, const int* in_sizes, int n_in,
                              void* d_out, int out_size, void* d_ws, size_t ws_size,
                              hipStream_t stream) {
    const float* g      = (const float*)d_in[0];  // guidance (B,8,H,W)
    const float* blur   = (const float*)d_in[1];  // blur_depth (B,1,H,W)
    const float* sparse = (const float*)d_in[2];  // sparse_depth (B,1,H,W)
    float* out = (float*)d_out;

    dim3 block(192, 1, 1);            // one row, 4 px/thread
    dim3 gridPre(1, HH, 2);           // precompute: 2 batches per dispatch
    dim3 gridStep(1, HH, BATCH);      // step: R3 config (2D, no swizzle)

    // fast path: fp16 AoS weights (16 B/px) + fp32 bias + ping buffer
    const size_t need_fast = (size_t)TOTAL * 16 + (size_t)TOTAL * 4 * 2;

    if (ws_size >= need_fast) {
        half8* w    = (half8*)d_ws;                       // TOTAL x 16 B
        float* bias = (float*)((char*)d_ws + (size_t)TOTAL * 16);
        float* r0   = bias + TOTAL;

        // Split into 4 dispatches (~24 us each) so step_kernel (~36 us)
        // dominates the rocprof top-5 and we finally see its counters.
        for (int b0 = 0; b0 < BATCH; b0 += 2)
            precompute_kernel<<<gridPre, block, 0, stream>>>(g, blur, sparse,
                                                             w, bias, b0);

        const float* prev = blur;
        for (int it = 0; it < NITER; ++it) {
            float* nxt = (it % 2 == 0) ? r0 : out;  // it=23 -> out
            step_kernel<<<gridStep, block, 0, stream>>>(w, bias, prev, nxt);
            prev = nxt;
        }
    } else {
        // Fallback: only one ping buffer in ws; recompute weights each step.
        dim3 block2(256, 1, 1);
        dim3 grid2(WW / 256, HH, BATCH);
        float* r0 = (float*)d_ws;
        const float* prev = blur;
        for (int it = 0; it < NITER; ++it) {
            float* nxt = (it % 2 == 0) ? r0 : out;
            step_recompute_kernel<<<grid2, block2, 0, stream>>>(g, blur, sparse,
                                                                prev, nxt);
            prev = nxt;
        }
    }
}